// Round 7
// baseline (201.340 us; speedup 1.0000x reference)
//
#include <hip/hip_runtime.h>

// PointTransformerLayer fused kernel (MI355X / gfx950) — round 7
//
// Math (bf16 path verified R2/R4/R6, absmax 0.03125):
//   relu1 = relu(aI_i - a_j)            aI = pos@pW1 + pb1, a = pos@pW1
//   S1    = [relu1 | (q_i - k_j)] @ [[W_pa],[aW1]]   (K=128), W_pa = pW2@aW1
//   H     = relu(S1 + c), c = ab1 + pb2@aW1          (c folded into G1 C-op)
//   simL2 = H @ (aW2*log2e)              (ab2 softmax-invariant -> dropped)
//   rpe   = relu1 @ pW2 ; vv = (v+pb2)_j + rpe       (v folded into G3 C-op)
//   out_i[d] = sum_j 2^simL2 * vv / sum_j 2^simL2
//
// R7 = R4 structure/ownership/layouts (133us known-good) + LOOP SKEW:
// iter n runs G1(n)+Hwrite(n) and G2/G3/softmax(n-1) in ONE barrier-free
// region, so the 16 H-frag ds_read_b128s drain under G1's 32 MFMAs instead
// of stalling right after the barrier (R4's ~48% stall). G3 relu1-frags and
// vj carried in registers across one iter. R6's W2f expansion REVERTED
// (register cost > LDS win: AGPR-move VALU overhead, 144us).

typedef float f32x4 __attribute__((ext_vector_type(4)));
using sh8 = __attribute__((ext_vector_type(8))) short;  // 8 bf16 (4 VGPRs)

static constexpr int NPTS = 1024;

// ---- ws layout (bytes) — identical to round 4 ----
static constexpr size_t BEXT_OFF = 0;        // 4*16*64*8 bf16  = 65536 B
static constexpr size_t AW2F_OFF = 65536;    // 8*4*64*8 bf16   = 32768 B
static constexpr size_t PW2F_OFF = 98304;    // 2*4*64*8 bf16   = 8192 B
static constexpr size_t CARR_OFF = 106496;   // 256 f32         = 1024 B
static constexpr size_t AI_OFF   = 107520;   // 1024*64 f32 (+pb1)
static constexpr size_t QI_OFF   = 369664;   // 1024*64 f32
static constexpr size_t VPT_OFF  = 631808;   // 64*1024 f32 (v+pb2, transposed)
static constexpr size_t AJ_OFF   = 893952;   // 1024*64 bf16
static constexpr size_t KN_OFF   = 1025024;  // 1024*64 bf16 (negated k)

__device__ __forceinline__ unsigned short f2b_rne(float f) {
    unsigned u = __float_as_uint(f);
    u += 0x7fffu + ((u >> 16) & 1u);
    return (unsigned short)(u >> 16);
}
// trunc-pack two f32 into bf16x2 — single v_perm_b32
__device__ __forceinline__ unsigned pk2(float lo, float hi) {
    return __builtin_amdgcn_perm(__float_as_uint(hi), __float_as_uint(lo), 0x07060302);
}
__device__ __forceinline__ float b2f(unsigned short s) {
    return __uint_as_float(((unsigned)s) << 16);
}

// ---------------- combined prep: weights (blocks 0..208) + points (209..464) ----------------
__global__ void prep_all(const float* __restrict__ x, const float* __restrict__ pos,
                         const float* __restrict__ Wq, const float* __restrict__ Wk,
                         const float* __restrict__ Wv, const float* __restrict__ pW1,
                         const float* __restrict__ pb1, const float* __restrict__ pW2,
                         const float* __restrict__ pb2, const float* __restrict__ aW1,
                         const float* __restrict__ ab1, const float* __restrict__ aW2,
                         unsigned short* __restrict__ bextf, unsigned short* __restrict__ aw2f,
                         unsigned short* __restrict__ pw2f, float* __restrict__ cArr,
                         float* __restrict__ qI, unsigned short* __restrict__ kN,
                         float* __restrict__ vPT, float* __restrict__ aI,
                         unsigned short* __restrict__ aJ)
{
    const int b = blockIdx.x;
    if (b < 209) {
        const int idx = b * 256 + threadIdx.x;
        if (idx < 32768) {
            // B_ext[k][t]: k<64 -> W_pa = pW2@aW1, else aW1   (R2-verified)
            const int k = idx >> 8, t = idx & 255;
            float val;
            if (k < 64) {
                float s = 0.f;
                for (int d = 0; d < 64; ++d) s = fmaf(pW2[k * 64 + d], aW1[d * 256 + t], s);
                val = s;
            } else {
                val = aW1[(k - 64) * 256 + t];
            }
            const int kc = k >> 5, kl = k & 31, qq = kl >> 3, e = kl & 7;
            const int ntg = t >> 4, tl = t & 15;
            bextf[(((size_t)(kc * 16 + ntg) * 64) + (qq * 16 + tl)) * 8 + e] = f2b_rne(val);
        } else if (idx < 49152) {
            // aW2*log2e frags, permuted K matching H LDS layout (R2/R6-verified)
            const int r = idx - 32768;
            const int kp = r >> 6, d = r & 63;
            const int t = 64 * (kp >> 6) + 16 * (kp & 3) + ((kp >> 2) & 15);  // inverse perm
            const int kc = kp >> 5, kl = kp & 31, qq = kl >> 3, e = kl & 7;
            const int nt = d >> 4, dl = d & 15;
            aw2f[(((size_t)(kc * 4 + nt) * 64) + (qq * 16 + dl)) * 8 + e] =
                f2b_rne(aW2[t * 64 + d] * 1.4426950408889634f);
        } else if (idx < 53248) {
            // pW2 frags (R2-verified)
            const int r = idx - 49152;
            const int k = r >> 6, d = r & 63;
            const int kc = k >> 5, kl = k & 31, qq = kl >> 3, e = kl & 7;
            const int nt = d >> 4, dl = d & 15;
            pw2f[(((size_t)(kc * 4 + nt) * 64) + (qq * 16 + dl)) * 8 + e] = f2b_rne(pW2[k * 64 + d]);
        } else if (idx < 53504) {
            const int t = idx - 53248;
            float s = ab1[t];
            for (int d = 0; d < 64; ++d) s = fmaf(pb2[d], aW1[d * 256 + t], s);
            cArr[t] = s;
        }
    } else {
        // per-point prep: 4 points per block
        const int t = threadIdx.x, sub = t >> 6, d = t & 63;
        const int i = (b - 209) * 4 + sub;
        __shared__ float xs[4][64];
        xs[sub][d] = x[i * 64 + d];
        __syncthreads();
        float q = 0.f, k = 0.f, v = 0.f;
        for (int e = 0; e < 64; ++e) {
            const float xe = xs[sub][e];
            q = fmaf(xe, Wq[e * 64 + d], q);
            k = fmaf(xe, Wk[e * 64 + d], k);
            v = fmaf(xe, Wv[e * 64 + d], v);
        }
        const float a = pos[i * 2] * pW1[d] + pos[i * 2 + 1] * pW1[64 + d];
        qI[i * 64 + d] = q;
        kN[i * 64 + d] = f2b_rne(-k);
        vPT[d * NPTS + i] = v + pb2[d];
        aI[i * 64 + d] = a + pb1[d];
        aJ[i * 64 + d] = f2b_rne(a);
    }
}

// ---------------- main fused kernel: one block per query i, j-tile 32, skewed ----------------
__global__ __launch_bounds__(256, 2) void ptl_main(
    const float* __restrict__ aI, const float* __restrict__ qI,
    const unsigned short* __restrict__ aJ, const unsigned short* __restrict__ kN,
    const float* __restrict__ vPT,
    const unsigned short* __restrict__ bextf, const unsigned short* __restrict__ aw2f,
    const unsigned short* __restrict__ pw2f, const float* __restrict__ cArr,
    float* __restrict__ out)
{
    const int i    = blockIdx.x;
    const int tid  = threadIdx.x;
    const int w    = tid >> 6;    // wave: t-slice [64w,64w+64) for G1, d-slice [16w,16w+16) for G2/G3
    const int lane = tid & 63;
    const int m    = lane & 15;
    const int q    = lane >> 4;

    // double-buffered LDS: [buf][sub]
    __shared__ __align__(16) uint4 AfL[2][2][4][64];               // 16 KB
    __shared__ __align__(16) unsigned char Hs[2][2][16 * 528];     // 33 KB

    // constant B fragments (R4 set: 26 frags = 104 regs)
    sh8 Bf[16];
#pragma unroll
    for (int kc = 0; kc < 4; ++kc)
#pragma unroll
        for (int nt = 0; nt < 4; ++nt)
            Bf[kc * 4 + nt] = *(const sh8*)(bextf + ((size_t)((kc * 16 + 4 * w + nt) * 64 + lane)) * 8);
    sh8 W2f[8];
#pragma unroll
    for (int kc = 0; kc < 8; ++kc)
        W2f[kc] = *(const sh8*)(aw2f + ((size_t)((kc * 4 + w) * 64 + lane)) * 8);
    sh8 P2f[2];
#pragma unroll
    for (int kc = 0; kc < 2; ++kc)
        P2f[kc] = *(const sh8*)(pw2f + ((size_t)((kc * 4 + w) * 64 + lane)) * 8);

    float creg[4];
#pragma unroll
    for (int nt = 0; nt < 4; ++nt) creg[nt] = cArr[64 * w + 16 * nt + m];

    // builder: wave w builds A-frag k-block w (w<2: relu1 halves, w>=2: q-k halves)
    const int  half   = w & 1;
    const bool isRelu = (w < 2);
    const unsigned short* bsrc  = (isRelu ? aJ : kN) + m * 64 + half * 32 + q * 8;
    const float*          ibase = (isRelu ? aI : qI) + i * 64 + half * 32 + q * 8;
    float iv[8];
    *(float4*)(iv)     = *(const float4*)(ibase);
    *(float4*)(iv + 4) = *(const float4*)(ibase + 4);

    // prologue: build both subs of tile 0 into buffer 0
#pragma unroll
    for (int s = 0; s < 2; ++s) {
        const sh8 raw = *(const sh8*)(bsrc + (size_t)(16 * s) * 64);
        float t[8];
#pragma unroll
        for (int e = 0; e < 8; ++e)
            t[e] = isRelu ? fmaxf(iv[e] - b2f((unsigned short)raw[e]), 0.f)
                          : iv[e] + b2f((unsigned short)raw[e]);
        uint4 pk;
        pk.x = pk2(t[0], t[1]); pk.y = pk2(t[2], t[3]);
        pk.z = pk2(t[4], t[5]); pk.w = pk2(t[6], t[7]);
        AfL[0][s][w][lane] = pk;
    }
    __syncthreads();

    float num = 0.f, den = 0.f;
    const f32x4 z4 = {0.f, 0.f, 0.f, 0.f};
    const float* vbase = vPT + (size_t)(16 * w + m) * NPTS;

    sh8 pA00, pA01, pA10, pA11;  // relu1 frags of the not-yet-consumed tile (for G3)
    float vjp[8];                // vj of the not-yet-consumed tile

    // ---- iteration 0: front half only (G1 + H-write + build A(1)) ----
    {
        const sh8 A00 = *(const sh8*)&AfL[0][0][0][lane];
        const sh8 A01 = *(const sh8*)&AfL[0][0][1][lane];
        const sh8 A02 = *(const sh8*)&AfL[0][0][2][lane];
        const sh8 A03 = *(const sh8*)&AfL[0][0][3][lane];
        const sh8 A10 = *(const sh8*)&AfL[0][1][0][lane];
        const sh8 A11 = *(const sh8*)&AfL[0][1][1][lane];
        const sh8 A12 = *(const sh8*)&AfL[0][1][2][lane];
        const sh8 A13 = *(const sh8*)&AfL[0][1][3][lane];
        pA00 = A00; pA01 = A01; pA10 = A10; pA11 = A11;
        {
            f32x4 acc[4];
#pragma unroll
            for (int nt = 0; nt < 4; ++nt) {
                const f32x4 cv = {creg[nt], creg[nt], creg[nt], creg[nt]};
                acc[nt] = __builtin_amdgcn_mfma_f32_16x16x32_bf16(A00, Bf[0 * 4 + nt], cv, 0, 0, 0);
                acc[nt] = __builtin_amdgcn_mfma_f32_16x16x32_bf16(A01, Bf[1 * 4 + nt], acc[nt], 0, 0, 0);
                acc[nt] = __builtin_amdgcn_mfma_f32_16x16x32_bf16(A02, Bf[2 * 4 + nt], acc[nt], 0, 0, 0);
                acc[nt] = __builtin_amdgcn_mfma_f32_16x16x32_bf16(A03, Bf[3 * 4 + nt], acc[nt], 0, 0, 0);
            }
            unsigned char* hw = Hs[0][0] + (4 * q) * 528 + 128 * w + 8 * m;
#pragma unroll
            for (int r = 0; r < 4; ++r) {
                uint2 pk;
                pk.x = pk2(fmaxf(acc[0][r], 0.f), fmaxf(acc[1][r], 0.f));
                pk.y = pk2(fmaxf(acc[2][r], 0.f), fmaxf(acc[3][r], 0.f));
                *(uint2*)(hw + r * 528) = pk;
            }
        }
        {
            f32x4 acc[4];
#pragma unroll
            for (int nt = 0; nt < 4; ++nt) {
                const f32x4 cv = {creg[nt], creg[nt], creg[nt], creg[nt]};
                acc[nt] = __builtin_amdgcn_mfma_f32_16x16x32_bf16(A10, Bf[0 * 4 + nt], cv, 0, 0, 0);
                acc[nt] = __builtin_amdgcn_mfma_f32_16x16x32_bf16(A11, Bf[1 * 4 + nt], acc[nt], 0, 0, 0);
                acc[nt] = __builtin_amdgcn_mfma_f32_16x16x32_bf16(A12, Bf[2 * 4 + nt], acc[nt], 0, 0, 0);
                acc[nt] = __builtin_amdgcn_mfma_f32_16x16x32_bf16(A13, Bf[3 * 4 + nt], acc[nt], 0, 0, 0);
            }
            unsigned char* hw = Hs[0][1] + (4 * q) * 528 + 128 * w + 8 * m;
#pragma unroll
            for (int r = 0; r < 4; ++r) {
                uint2 pk;
                pk.x = pk2(fmaxf(acc[0][r], 0.f), fmaxf(acc[1][r], 0.f));
                pk.y = pk2(fmaxf(acc[2][r], 0.f), fmaxf(acc[3][r], 0.f));
                *(uint2*)(hw + r * 528) = pk;
            }
        }
        // build A(1) into buffer 1
#pragma unroll
        for (int s = 0; s < 2; ++s) {
            const sh8 raw = *(const sh8*)(bsrc + (size_t)(32 + 16 * s) * 64);
            float t[8];
#pragma unroll
            for (int e = 0; e < 8; ++e)
                t[e] = isRelu ? fmaxf(iv[e] - b2f((unsigned short)raw[e]), 0.f)
                              : iv[e] + b2f((unsigned short)raw[e]);
            uint4 pk;
            pk.x = pk2(t[0], t[1]); pk.y = pk2(t[2], t[3]);
            pk.z = pk2(t[4], t[5]); pk.w = pk2(t[6], t[7]);
            AfL[1][s][w][lane] = pk;
        }
        // vj(0)
        *(float4*)(vjp)     = *(const float4*)(vbase + 4 * q);
        *(float4*)(vjp + 4) = *(const float4*)(vbase + 16 + 4 * q);
    }
    __syncthreads();

    // ---- skewed main loop: iter n does G1(n) + G2/G3/softmax(n-1) ----
    for (int n = 1; n < 32; ++n) {
        const int pb = n & 1, hb = pb ^ 1;
        const int j0 = n << 5;

        // preload H-frags of tile n-1, sub0 (drain under G1's MFMAs)
        sh8 Hf[8];
#pragma unroll
        for (int kc = 0; kc < 8; ++kc)
            Hf[kc] = *(const sh8*)(Hs[hb][0] + m * 528 + kc * 64 + 16 * q);

        // A-frags of tile n
        const sh8 A00 = *(const sh8*)&AfL[pb][0][0][lane];
        const sh8 A01 = *(const sh8*)&AfL[pb][0][1][lane];
        const sh8 A02 = *(const sh8*)&AfL[pb][0][2][lane];
        const sh8 A03 = *(const sh8*)&AfL[pb][0][3][lane];
        const sh8 A10 = *(const sh8*)&AfL[pb][1][0][lane];
        const sh8 A11 = *(const sh8*)&AfL[pb][1][1][lane];
        const sh8 A12 = *(const sh8*)&AfL[pb][1][2][lane];
        const sh8 A13 = *(const sh8*)&AfL[pb][1][3][lane];

        // global loads for tile n+1 / tile n (early issue)
        sh8 raw0, raw1;
        if (n < 31) {
            raw0 = *(const sh8*)(bsrc + (size_t)(j0 + 32) * 64);
            raw1 = *(const sh8*)(bsrc + (size_t)(j0 + 48) * 64);
        }
        float vjc[8];
        *(float4*)(vjc)     = *(const float4*)(vbase + j0 + 4 * q);
        *(float4*)(vjc + 4) = *(const float4*)(vbase + j0 + 16 + 4 * q);

        // G1(n) sub0 + H-write
        {
            f32x4 acc[4];
#pragma unroll
            for (int nt = 0; nt < 4; ++nt) {
                const f32x4 cv = {creg[nt], creg[nt], creg[nt], creg[nt]};
                acc[nt] = __builtin_amdgcn_mfma_f32_16x16x32_bf16(A00, Bf[0 * 4 + nt], cv, 0, 0, 0);
                acc[nt] = __builtin_amdgcn_mfma_f32_16x16x32_bf16(A01, Bf[1 * 4 + nt], acc[nt], 0, 0, 0);
                acc[nt] = __builtin_amdgcn_mfma_f32_16x16x32_bf16(A02, Bf[2 * 4 + nt], acc[nt], 0, 0, 0);
                acc[nt] = __builtin_amdgcn_mfma_f32_16x16x32_bf16(A03, Bf[3 * 4 + nt], acc[nt], 0, 0, 0);
            }
            unsigned char* hw = Hs[pb][0] + (4 * q) * 528 + 128 * w + 8 * m;
#pragma unroll
            for (int r = 0; r < 4; ++r) {
                uint2 pk;
                pk.x = pk2(fmaxf(acc[0][r], 0.f), fmaxf(acc[1][r], 0.f));
                pk.y = pk2(fmaxf(acc[2][r], 0.f), fmaxf(acc[3][r], 0.f));
                *(uint2*)(hw + r * 528) = pk;
            }
        }
        // G1(n) sub1 + H-write
        {
            f32x4 acc[4];
#pragma unroll
            for (int nt = 0; nt < 4; ++nt) {
                const f32x4 cv = {creg[nt], creg[nt], creg[nt], creg[nt]};
                acc[nt] = __builtin_amdgcn_mfma_f32_16x16x32_bf16(A10, Bf[0 * 4 + nt], cv, 0, 0, 0);
                acc[nt] = __builtin_amdgcn_mfma_f32_16x16x32_bf16(A11, Bf[1 * 4 + nt], acc[nt], 0, 0, 0);
                acc[nt] = __builtin_amdgcn_mfma_f32_16x16x32_bf16(A12, Bf[2 * 4 + nt], acc[nt], 0, 0, 0);
                acc[nt] = __builtin_amdgcn_mfma_f32_16x16x32_bf16(A13, Bf[3 * 4 + nt], acc[nt], 0, 0, 0);
            }
            unsigned char* hw = Hs[pb][1] + (4 * q) * 528 + 128 * w + 8 * m;
#pragma unroll
            for (int r = 0; r < 4; ++r) {
                uint2 pk;
                pk.x = pk2(fmaxf(acc[0][r], 0.f), fmaxf(acc[1][r], 0.f));
                pk.y = pk2(fmaxf(acc[2][r], 0.f), fmaxf(acc[3][r], 0.f));
                *(uint2*)(hw + r * 528) = pk;
            }
        }

        // build A(n+1) into the other buffer
        if (n < 31) {
#pragma unroll
            for (int s = 0; s < 2; ++s) {
                const sh8 raw = s ? raw1 : raw0;
                float t[8];
#pragma unroll
                for (int e = 0; e < 8; ++e)
                    t[e] = isRelu ? fmaxf(iv[e] - b2f((unsigned short)raw[e]), 0.f)
                                  : iv[e] + b2f((unsigned short)raw[e]);
                uint4 pk;
                pk.x = pk2(t[0], t[1]); pk.y = pk2(t[2], t[3]);
                pk.z = pk2(t[4], t[5]); pk.w = pk2(t[6], t[7]);
                AfL[hb][s][w][lane] = pk;
            }
        }

        // G2(n-1) sub0 — preloaded frags
        f32x4 aS0 = z4;
#pragma unroll
        for (int kc = 0; kc < 8; ++kc)
            aS0 = __builtin_amdgcn_mfma_f32_16x16x32_bf16(Hf[kc], W2f[kc], aS0, 0, 0, 0);
        // G2(n-1) sub1 — inline reads (hide under sub0's MFMAs)
        f32x4 aS1 = z4;
#pragma unroll
        for (int kc = 0; kc < 8; ++kc) {
            const sh8 hf = *(const sh8*)(Hs[hb][1] + m * 528 + kc * 64 + 16 * q);
            aS1 = __builtin_amdgcn_mfma_f32_16x16x32_bf16(hf, W2f[kc], aS1, 0, 0, 0);
        }
        // G3(n-1): rpe + v (C-op), relu1 frags from carried registers
        const f32x4 vc0 = {vjp[0], vjp[1], vjp[2], vjp[3]};
        const f32x4 vc1 = {vjp[4], vjp[5], vjp[6], vjp[7]};
        f32x4 aR0 = __builtin_amdgcn_mfma_f32_16x16x32_bf16(pA00, P2f[0], vc0, 0, 0, 0);
        aR0 = __builtin_amdgcn_mfma_f32_16x16x32_bf16(pA01, P2f[1], aR0, 0, 0, 0);
        f32x4 aR1 = __builtin_amdgcn_mfma_f32_16x16x32_bf16(pA10, P2f[0], vc1, 0, 0, 0);
        aR1 = __builtin_amdgcn_mfma_f32_16x16x32_bf16(pA11, P2f[1], aR1, 0, 0, 0);

        // softmax(n-1) accumulation
#pragma unroll
        for (int r = 0; r < 4; ++r) {
            const float e0 = exp2f(aS0[r]);
            num = fmaf(e0, aR0[r], num);
            den += e0;
            const float e1 = exp2f(aS1[r]);
            num = fmaf(e1, aR1[r], num);
            den += e1;
        }

        // rotate carried state
        pA00 = A00; pA01 = A01; pA10 = A10; pA11 = A11;
#pragma unroll
        for (int e = 0; e < 8; ++e) vjp[e] = vjc[e];

        __syncthreads();  // publishes Hs[pb][*] and AfL[hb][*]
    }

    // ---- epilogue: consume tile 31 (Hs[1]) ----
    {
        f32x4 aS0 = z4, aS1 = z4;
#pragma unroll
        for (int kc = 0; kc < 8; ++kc) {
            const sh8 hf0 = *(const sh8*)(Hs[1][0] + m * 528 + kc * 64 + 16 * q);
            aS0 = __builtin_amdgcn_mfma_f32_16x16x32_bf16(hf0, W2f[kc], aS0, 0, 0, 0);
            const sh8 hf1 = *(const sh8*)(Hs[1][1] + m * 528 + kc * 64 + 16 * q);
            aS1 = __builtin_amdgcn_mfma_f32_16x16x32_bf16(hf1, W2f[kc], aS1, 0, 0, 0);
        }
        const f32x4 vc0 = {vjp[0], vjp[1], vjp[2], vjp[3]};
        const f32x4 vc1 = {vjp[4], vjp[5], vjp[6], vjp[7]};
        f32x4 aR0 = __builtin_amdgcn_mfma_f32_16x16x32_bf16(pA00, P2f[0], vc0, 0, 0, 0);
        aR0 = __builtin_amdgcn_mfma_f32_16x16x32_bf16(pA01, P2f[1], aR0, 0, 0, 0);
        f32x4 aR1 = __builtin_amdgcn_mfma_f32_16x16x32_bf16(pA10, P2f[0], vc1, 0, 0, 0);
        aR1 = __builtin_amdgcn_mfma_f32_16x16x32_bf16(pA11, P2f[1], aR1, 0, 0, 0);
#pragma unroll
        for (int r = 0; r < 4; ++r) {
            const float e0 = exp2f(aS0[r]);
            num = fmaf(e0, aR0[r], num);
            den += e0;
            const float e1 = exp2f(aS1[r]);
            num = fmaf(e1, aR1[r], num);
            den += e1;
        }
    }

    // reduce the 4 quad-partials (lanes m, m+16, m+32, m+48)
    num += __shfl_xor(num, 16);
    num += __shfl_xor(num, 32);
    den += __shfl_xor(den, 16);
    den += __shfl_xor(den, 32);
    if (q == 0) out[i * 64 + 16 * w + m] = num / den;
}

extern "C" void kernel_launch(void* const* d_in, const int* in_sizes, int n_in,
                              void* d_out, int out_size, void* d_ws, size_t ws_size,
                              hipStream_t stream) {
    const float* x   = (const float*)d_in[0];
    const float* pos = (const float*)d_in[1];
    const float* Wq  = (const float*)d_in[2];
    const float* Wk  = (const float*)d_in[3];
    const float* Wv  = (const float*)d_in[4];
    const float* pW1 = (const float*)d_in[5];
    const float* pb1 = (const float*)d_in[6];
    const float* pW2 = (const float*)d_in[7];
    const float* pb2 = (const float*)d_in[8];
    const float* aW1 = (const float*)d_in[9];
    const float* ab1 = (const float*)d_in[10];
    const float* aW2 = (const float*)d_in[11];
    // d_in[12] = ab2: constant over j -> cancels in per-channel softmax, unused.

    char* ws = (char*)d_ws;
    unsigned short* bextf = (unsigned short*)(ws + BEXT_OFF);
    unsigned short* aw2f  = (unsigned short*)(ws + AW2F_OFF);
    unsigned short* pw2f  = (unsigned short*)(ws + PW2F_OFF);
    float*          cArr  = (float*)(ws + CARR_OFF);
    float*          aIa   = (float*)(ws + AI_OFF);
    float*          qIa   = (float*)(ws + QI_OFF);
    float*          vPTa  = (float*)(ws + VPT_OFF);
    unsigned short* aJa   = (unsigned short*)(ws + AJ_OFF);
    unsigned short* kNa   = (unsigned short*)(ws + KN_OFF);

    prep_all<<<465, 256, 0, stream>>>(x, pos, Wq, Wk, Wv, pW1, pb1, pW2, pb2, aW1, ab1, aW2,
                                      bextf, aw2f, pw2f, cArr, qIa, kNa, vPTa, aIa, aJa);
    ptl_main<<<NPTS, 256, 0, stream>>>(aIa, qIa, aJa, kNa, vPTa, bextf, aw2f, pw2f, cArr,
                                       (float*)d_out);
}